// Round 21
// baseline (113.439 us; speedup 1.0000x reference)
//
#include <hip/hip_runtime.h>
#include <hip/hip_bf16.h>

// FiLM + 2-layer preact resnet. N=65536, H=256, C=512.
// Round 21: 64-VGPR / 32-waves-per-CU retry built ONLY from proven pieces.
// 1024-thr blocks (16 waves) x 32 rows. Per wave: gamma nt=w + beta nt=16+w
// -> accg[2]+accb[2]=16 regs (r12-K1's proven single-pass loop). cond staged
// monolithically [32][512] bf16 = 32KB (r18's proven staging; no DMA races).
// FiLM from regs + LDS x (r12-K1), r1->B half, r2->A half, GEMM2/3 single
// n-tile with named 2-slot B pipeline (rolled outer loops), r18 fp32-LDS
// epilogue with global x re-read (L3-warm). LDS 32KB; launch_bounds(1024,4)
// -> 64-reg box (law: box = 256/arg2); est. live ~62.

typedef __attribute__((ext_vector_type(8))) short bf16x8;   // 8 bf16 = 4 VGPR
typedef __attribute__((ext_vector_type(4))) float f32x4;    // MFMA C/D

typedef unsigned short ushort_t;
typedef unsigned int uint_t;

__device__ __forceinline__ ushort_t f2bfh(float f) {
  __hip_bfloat16 h = __float2bfloat16(f);            // RNE, hw cvt
  return *reinterpret_cast<ushort_t*>(&h);
}
__device__ __forceinline__ float bf2f(ushort_t s) {
  union { uint_t u; float f; } v; v.u = ((uint_t)s) << 16;
  return v.f;
}
__device__ __forceinline__ bf16x8 ldfrag(const ushort_t* p) {
  return *reinterpret_cast<const bf16x8*>(p);
}
__device__ __forceinline__ bf16x8 pack8(float4 a, float4 b) {
  union { bf16x8 v; __hip_bfloat162 h[4]; } u;       // v_cvt_pk_bf16_f32 x4
  u.h[0] = __float22bfloat162_rn(float2{a.x, a.y});
  u.h[1] = __float22bfloat162_rn(float2{a.z, a.w});
  u.h[2] = __float22bfloat162_rn(float2{b.x, b.y});
  u.h[3] = __float22bfloat162_rn(float2{b.z, b.w});
  return u.v;
}

// ---------------------------------------------------------------------------
// Pack weights (fp32 row-major [K][Ncols]) into bf16 MFMA-B fragment order:
//   p[((nt*KT + kt)*64 + lane)*8 + j] = W[kt*32 + (lane>>4)*8 + j][nt*16 + (lane&15)]
// ---------------------------------------------------------------------------
__global__ void pack_weights(const float* __restrict__ Wf,
                             const float* __restrict__ W1,
                             const float* __restrict__ W2,
                             ushort_t* __restrict__ p1,
                             ushort_t* __restrict__ pW1,
                             ushort_t* __restrict__ pW2) {
  int u = blockIdx.x * 256 + threadIdx.x;
  if (u < 32768) {
    int lane = u & 63, rest = u >> 6;
    int kt = rest & 15;
    int kb = kt * 32 + (lane >> 4) * 8;
    int col = (rest >> 4) * 16 + (lane & 15);
#pragma unroll
    for (int j = 0; j < 8; ++j)
      p1[(size_t)u * 8 + j] = f2bfh(Wf[(size_t)(kb + j) * 512 + col]);
  } else if (u < 40960) {
    int v = u - 32768;
    int lane = v & 63;
    int kt = (v >> 6) & 7;
    int kb = kt * 32 + (lane >> 4) * 8;
    int col = (v >> 9) * 16 + (lane & 15);
#pragma unroll
    for (int j = 0; j < 8; ++j)
      pW1[(size_t)v * 8 + j] = f2bfh(W1[(size_t)(kb + j) * 256 + col]);
  } else if (u < 49152) {
    int v = u - 40960;
    int lane = v & 63;
    int kt = (v >> 6) & 7;
    int kb = kt * 32 + (lane >> 4) * 8;
    int col = (v >> 9) * 16 + (lane & 15);
#pragma unroll
    for (int j = 0; j < 8; ++j)
      pW2[(size_t)v * 8 + j] = f2bfh(W2[(size_t)(kb + j) * 256 + col]);
  }
}

// ---------------------------------------------------------------------------
// Fused: 2048 blocks x 32 rows, 16 waves (1024 thr). LDS 32KB:
//   phase 1: cond bf16 [32][512] (1KB/row) across whole LDS
//   phase 2: A=[0,16K) x bf16 [32][256] -> r2 ; B=[16K,32K) r1 bf16 [32][256]
//   phase 3: fp32 out tile [32][256] (1KB/row) across whole LDS
// XOR swizzle everywhere: byte ^= (row&15)<<4 (row<32; same family as r18).
// GEMM1: wave w owns gamma nt=w and beta nt=16+w -> accg[2]+accb[2].
// GEMM2/3: wave w owns H nt=w -> acc[2].
// ---------------------------------------------------------------------------
__global__ __launch_bounds__(1024, 4)
void film_fused(const float* __restrict__ x, const float* __restrict__ cond,
                const float* __restrict__ b_film, const float* __restrict__ b1,
                const float* __restrict__ b2,
                const ushort_t* __restrict__ p1, const ushort_t* __restrict__ pW1,
                const ushort_t* __restrict__ pW2, float* __restrict__ out) {
  __shared__ __align__(16) char lds[32768];
  char* A = lds;
  char* B = lds + 16384;
  const int r0 = blockIdx.x * 32;
  const int t = threadIdx.x;      // 0..1023
  const int w = t >> 6;           // 0..15
  const int l = t & 63;
  const int l15 = l & 15;
  const int lhi = l >> 4;

  const float bgv = b_film[w * 16 + l15];
  const float bbv = b_film[256 + w * 16 + l15];
  const float b1v = b1[w * 16 + l15];
  const float b2v = b2[w * 16 + l15];

  // ---- stage cond [32][512] -> bf16 LDS (r18's proven pattern, halved)
#pragma unroll
  for (int it = 0; it < 2; ++it) {
    int u = it * 1024 + t;
    int row = u >> 6, k8 = u & 63;   // [32 rows][64 units of 8 cols]
    const float4* cs = reinterpret_cast<const float4*>(cond + (size_t)(r0 + row) * 512 + k8 * 8);
    float4 a = cs[0], b = cs[1];
    int byte = row * 1024 + k8 * 16;
    byte ^= ((row & 15) << 4);
    *reinterpret_cast<bf16x8*>(lds + byte) = pack8(a, b);
  }
  // GEMM1 B preload kt=0 (gamma panel w, beta panel 16+w)
  bf16x8 bcg = ldfrag(p1 + ((size_t)(w * 16 + 0) * 64 + l) * 8);
  bf16x8 bcb = ldfrag(p1 + ((size_t)((16 + w) * 16 + 0) * 64 + l) * 8);
  __syncthreads();   // B1: cond staged

  // ---- GEMM1: single pass, gamma+beta together (r12-K1's proven loop)
  f32x4 accg[2], accb[2];
#pragma unroll
  for (int m = 0; m < 2; ++m) {
    accg[m] = (f32x4){0.f, 0.f, 0.f, 0.f};
    accb[m] = (f32x4){0.f, 0.f, 0.f, 0.f};
  }

#pragma unroll 1
  for (int kp = 0; kp < 8; ++kp) {
    const int kt0 = kp * 2;
    bf16x8 bng = ldfrag(p1 + ((size_t)(w * 16 + kt0 + 1) * 64 + l) * 8);
    bf16x8 bnb = ldfrag(p1 + ((size_t)((16 + w) * 16 + kt0 + 1) * 64 + l) * 8);
    __builtin_amdgcn_s_setprio(1);
#pragma unroll
    for (int m = 0; m < 2; ++m) {
      int row = m * 16 + l15;
      int byte = row * 1024 + kt0 * 64 + lhi * 16;
      byte ^= ((row & 15) << 4);
      bf16x8 a = *reinterpret_cast<const bf16x8*>(lds + byte);
      accg[m] = __builtin_amdgcn_mfma_f32_16x16x32_bf16(a, bcg, accg[m], 0, 0, 0);
      accb[m] = __builtin_amdgcn_mfma_f32_16x16x32_bf16(a, bcb, accb[m], 0, 0, 0);
    }
    __builtin_amdgcn_s_setprio(0);
    if (kt0 + 2 < 16) {
      bcg = ldfrag(p1 + ((size_t)(w * 16 + kt0 + 2) * 64 + l) * 8);
      bcb = ldfrag(p1 + ((size_t)((16 + w) * 16 + kt0 + 2) * 64 + l) * 8);
    }
    __builtin_amdgcn_s_setprio(1);
#pragma unroll
    for (int m = 0; m < 2; ++m) {
      int row = m * 16 + l15;
      int byte = row * 1024 + (kt0 + 1) * 64 + lhi * 16;
      byte ^= ((row & 15) << 4);
      bf16x8 a = *reinterpret_cast<const bf16x8*>(lds + byte);
      accg[m] = __builtin_amdgcn_mfma_f32_16x16x32_bf16(a, bng, accg[m], 0, 0, 0);
      accb[m] = __builtin_amdgcn_mfma_f32_16x16x32_bf16(a, bnb, accb[m], 0, 0, 0);
    }
    __builtin_amdgcn_s_setprio(0);
  }
  __syncthreads();   // B2: all cond reads done -> LDS reusable

  // ---- x -> A [32][256] bf16 swz (one 16B unit per thread)
  {
    int row = t >> 5, c8 = t & 31;
    const float4* xs = reinterpret_cast<const float4*>(x + (size_t)(r0 + row) * 256 + c8 * 8);
    float4 xa = xs[0], xb = xs[1];
    int byte = row * 512 + c8 * 16;
    byte ^= ((row & 15) << 4);
    *reinterpret_cast<bf16x8*>(A + byte) = pack8(xa, xb);
  }
  __syncthreads();   // B3: x staged

  // ---- FiLM from registers (r12-K1's proven pattern): r1 -> B
#pragma unroll
  for (int m = 0; m < 2; ++m) {
#pragma unroll
    for (int reg = 0; reg < 4; ++reg) {
      int row = m * 16 + lhi * 4 + reg;
      int col = w * 16 + l15;
      int byte = row * 512 + col * 2;
      byte ^= ((row & 15) << 4);
      float xv = bf2f(*reinterpret_cast<const ushort_t*>(A + byte));
      float hv = fmaxf((accg[m][reg] + bgv) * xv + (accb[m][reg] + bbv), 0.f);
      *reinterpret_cast<ushort_t*>(B + byte) = f2bfh(hv);
    }
  }
  // GEMM2 B preload
  bf16x8 c2 = ldfrag(pW1 + ((size_t)(w * 8 + 0) * 64 + l) * 8);
  __syncthreads();   // B4: r1 ready

  // ---- GEMM2: acc2 = r1 @ W1 (nt=w), named 2-slot pipeline
  f32x4 acc2[2];
#pragma unroll
  for (int m = 0; m < 2; ++m) acc2[m] = (f32x4){0.f, 0.f, 0.f, 0.f};

#pragma unroll 1
  for (int kp = 0; kp < 4; ++kp) {
    const int kt0 = kp * 2;
    bf16x8 n2 = ldfrag(pW1 + ((size_t)(w * 8 + kt0 + 1) * 64 + l) * 8);
    __builtin_amdgcn_s_setprio(1);
#pragma unroll
    for (int m = 0; m < 2; ++m) {
      int row = m * 16 + l15;
      int byte = row * 512 + kt0 * 64 + lhi * 16;
      byte ^= ((row & 15) << 4);
      bf16x8 a = *reinterpret_cast<const bf16x8*>(B + byte);
      acc2[m] = __builtin_amdgcn_mfma_f32_16x16x32_bf16(a, c2, acc2[m], 0, 0, 0);
    }
    __builtin_amdgcn_s_setprio(0);
    if (kt0 + 2 < 8) c2 = ldfrag(pW1 + ((size_t)(w * 8 + kt0 + 2) * 64 + l) * 8);
    __builtin_amdgcn_s_setprio(1);
#pragma unroll
    for (int m = 0; m < 2; ++m) {
      int row = m * 16 + l15;
      int byte = row * 512 + (kt0 + 1) * 64 + lhi * 16;
      byte ^= ((row & 15) << 4);
      bf16x8 a = *reinterpret_cast<const bf16x8*>(B + byte);
      acc2[m] = __builtin_amdgcn_mfma_f32_16x16x32_bf16(a, n2, acc2[m], 0, 0, 0);
    }
    __builtin_amdgcn_s_setprio(0);
  }
  // r2 = relu(acc2+b1) -> A (x dead after B4; other waves only read B here)
#pragma unroll
  for (int m = 0; m < 2; ++m) {
#pragma unroll
    for (int reg = 0; reg < 4; ++reg) {
      int row = m * 16 + lhi * 4 + reg;
      int col = w * 16 + l15;
      int byte = row * 512 + col * 2;
      byte ^= ((row & 15) << 4);
      *reinterpret_cast<ushort_t*>(A + byte) = f2bfh(fmaxf(acc2[m][reg] + b1v, 0.f));
    }
  }
  bf16x8 c3 = ldfrag(pW2 + ((size_t)(w * 8 + 0) * 64 + l) * 8);
  __syncthreads();   // B5: r2 ready

  // ---- GEMM3: acc3 = r2 @ W2 (nt=w)
  f32x4 acc3[2];
#pragma unroll
  for (int m = 0; m < 2; ++m) acc3[m] = (f32x4){0.f, 0.f, 0.f, 0.f};

#pragma unroll 1
  for (int kp = 0; kp < 4; ++kp) {
    const int kt0 = kp * 2;
    bf16x8 n3 = ldfrag(pW2 + ((size_t)(w * 8 + kt0 + 1) * 64 + l) * 8);
    __builtin_amdgcn_s_setprio(1);
#pragma unroll
    for (int m = 0; m < 2; ++m) {
      int row = m * 16 + l15;
      int byte = row * 512 + kt0 * 64 + lhi * 16;
      byte ^= ((row & 15) << 4);
      bf16x8 a = *reinterpret_cast<const bf16x8*>(A + byte);
      acc3[m] = __builtin_amdgcn_mfma_f32_16x16x32_bf16(a, c3, acc3[m], 0, 0, 0);
    }
    __builtin_amdgcn_s_setprio(0);
    if (kt0 + 2 < 8) c3 = ldfrag(pW2 + ((size_t)(w * 8 + kt0 + 2) * 64 + l) * 8);
    __builtin_amdgcn_s_setprio(1);
#pragma unroll
    for (int m = 0; m < 2; ++m) {
      int row = m * 16 + l15;
      int byte = row * 512 + (kt0 + 1) * 64 + lhi * 16;
      byte ^= ((row & 15) << 4);
      bf16x8 a = *reinterpret_cast<const bf16x8*>(A + byte);
      acc3[m] = __builtin_amdgcn_mfma_f32_16x16x32_bf16(a, n3, acc3[m], 0, 0, 0);
    }
    __builtin_amdgcn_s_setprio(0);
  }
  __syncthreads();   // B6: all r2 reads done -> whole LDS free

  // ---- epilogue: fp32 [32][256] across whole LDS, +b2 at dump,
  // +x (L3-warm global re-read) at coalesced nontemporal store (r18 proven)
#pragma unroll
  for (int m = 0; m < 2; ++m) {
#pragma unroll
    for (int reg = 0; reg < 4; ++reg) {
      int row = m * 16 + lhi * 4 + reg;
      int col = w * 16 + l15;
      int byte = row * 1024 + col * 4;
      byte ^= ((row & 15) << 4);
      *reinterpret_cast<float*>(lds + byte) = acc3[m][reg] + b2v;
    }
  }
  __syncthreads();   // B7: tile ready
#pragma unroll
  for (int i = 0; i < 2; ++i) {
    int u = i * 1024 + t;
    int row = u >> 6, c4 = u & 63;   // [32 rows][64 units of 4 cols]
    int byte = row * 1024 + c4 * 16;
    byte ^= ((row & 15) << 4);
    f32x4 v = *reinterpret_cast<const f32x4*>(lds + byte);
    const float4 xres = *reinterpret_cast<const float4*>(
        x + (size_t)(r0 + row) * 256 + c4 * 4);
    v.x += xres.x; v.y += xres.y; v.z += xres.z; v.w += xres.w;
    f32x4* op = reinterpret_cast<f32x4*>(out + (size_t)(r0 + row) * 256 + c4 * 4);
    __builtin_nontemporal_store(v, op);
  }
}

extern "C" void kernel_launch(void* const* d_in, const int* in_sizes, int n_in,
                              void* d_out, int out_size, void* d_ws, size_t ws_size,
                              hipStream_t stream) {
  const float* x      = (const float*)d_in[0];
  const float* cond   = (const float*)d_in[1];
  const float* W_film = (const float*)d_in[2];
  const float* b_film = (const float*)d_in[3];
  const float* W1     = (const float*)d_in[4];
  const float* b1     = (const float*)d_in[5];
  const float* W2     = (const float*)d_in[6];
  const float* b2     = (const float*)d_in[7];
  float* out = (float*)d_out;

  ushort_t* p1  = (ushort_t*)d_ws;       // 512KB
  ushort_t* pW1 = p1 + 262144;           // 128KB
  ushort_t* pW2 = pW1 + 65536;           // 128KB

  hipLaunchKernelGGL(pack_weights, dim3(192), dim3(256), 0, stream,
                     W_film, W1, W2, p1, pW1, pW2);
  hipLaunchKernelGGL(film_fused, dim3(2048), dim3(1024), 0, stream,
                     x, cond, b_film, b1, b2, p1, pW1, pW2, out);
}